// Round 2
// baseline (289.462 us; speedup 1.0000x reference)
//
#include <hip/hip_runtime.h>

#define N_NODES 50000
#define N_EDGES 800000
#define N_GRAPHS 512
#define DIM 128
#define N_PAD 50048

#define BW_LOG 9
#define BWID 512                                  // nodes per bucket
#define NB ((N_NODES + BWID - 1) / BWID)          // 98
#define CHUNK 4096                                // edges per phase-A block
#define NCHUNK ((N_EDGES + CHUNK - 1) / CHUNK)    // 196

typedef unsigned int uint;
typedef unsigned short ushort;
typedef __attribute__((ext_vector_type(8))) short bf16x8;
typedef __attribute__((ext_vector_type(4))) float f32x4;

// bf16 helpers (RNE pack, cheap unpack)
__device__ __forceinline__ ushort f2bf(float f) {
    uint u = __float_as_uint(f);
    return (ushort)((u + 0x7fffu + ((u >> 16) & 1u)) >> 16);
}
__device__ __forceinline__ float bf2f(ushort h) { return __uint_as_float((uint)h << 16); }
__device__ __forceinline__ float bflo(uint p) { return __uint_as_float(p << 16); }
__device__ __forceinline__ float bfhi(uint p) { return __uint_as_float(p & 0xffff0000u); }

// ---------------- CSR build: bucket-sorted ----------------

__global__ __launch_bounds__(256) void bhist_k(const int* __restrict__ dst,
                                               int* __restrict__ bcnt_pad, int e) {
    __shared__ int h[NB];
    int t = threadIdx.x;
    for (int i = t; i < NB; i += 256) h[i] = 0;
    __syncthreads();
    int base = blockIdx.x * CHUNK;
    for (int i = t; i < CHUNK; i += 256) {
        int idx = base + i;
        if (idx < e) atomicAdd(&h[dst[idx] >> BW_LOG], 1);
    }
    __syncthreads();
    for (int i = t; i < NB; i += 256)
        if (h[i]) atomicAdd(&bcnt_pad[i << 4], h[i]);
}

// parallel 98-wide exclusive scan (one 128-thread block)
__global__ void bscan_k(const int* __restrict__ bcnt_pad, int* __restrict__ bbase,
                        int* __restrict__ bcur_pad) {
    __shared__ int v[128];
    int t = threadIdx.x;
    int x = (t < NB) ? bcnt_pad[t << 4] : 0;
    v[t] = x;
    __syncthreads();
    for (int o = 1; o < 128; o <<= 1) {
        int val = v[t];
        int add = (t >= o) ? v[t - o] : 0;
        __syncthreads();
        v[t] = val + add;
        __syncthreads();
    }
    if (t < NB) {
        int excl = (t == 0) ? 0 : v[t - 1];
        bbase[t] = excl;
        bcur_pad[t << 4] = excl;
    }
    if (t == NB - 1) bbase[NB] = v[t];
}

// packed record: (src << 9) | (dst & 511)
__global__ __launch_bounds__(256) void bscat_k(const int* __restrict__ src,
                                               const int* __restrict__ dst,
                                               int* __restrict__ bcur_pad,
                                               uint* __restrict__ stage, int e) {
    __shared__ int h[NB];
    __shared__ int bb[NB];
    __shared__ int lc[NB];
    int t = threadIdx.x;
    for (int i = t; i < NB; i += 256) h[i] = 0;
    __syncthreads();
    int base = blockIdx.x * CHUNK;
    for (int i = t; i < CHUNK; i += 256) {
        int idx = base + i;
        if (idx < e) atomicAdd(&h[dst[idx] >> BW_LOG], 1);
    }
    __syncthreads();
    for (int i = t; i < NB; i += 256) {
        int c = h[i];
        bb[i] = c ? atomicAdd(&bcur_pad[i << 4], c) : 0;
        lc[i] = 0;
    }
    __syncthreads();
    for (int i = t; i < CHUNK; i += 256) {
        int idx = base + i;
        if (idx < e) {
            int d = dst[idx];
            int b = d >> BW_LOG;
            int r = atomicAdd(&lc[b], 1);
            stage[bb[b] + r] = ((uint)src[idx] << BW_LOG) | (uint)(d & (BWID - 1));
        }
    }
}

__global__ __launch_bounds__(256) void csr_k(const uint* __restrict__ stage,
                                             const int* __restrict__ bbase,
                                             int* __restrict__ row_ptr,
                                             float* __restrict__ dis,
                                             int* __restrict__ col) {
    __shared__ int hist[BWID];
    __shared__ int excl[BWID];
    __shared__ int ws[256];
    int b = blockIdx.x, t = threadIdx.x;
    int beg = bbase[b], end = bbase[b + 1];
    for (int i = t; i < BWID; i += 256) hist[i] = 0;
    __syncthreads();
    for (int i = beg + t; i < end; i += 256)
        atomicAdd(&hist[stage[i] & (BWID - 1)], 1);
    __syncthreads();
    int s = hist[2 * t] + hist[2 * t + 1];
    ws[t] = s;
    __syncthreads();
    for (int o = 1; o < 256; o <<= 1) {
        int v = ws[t];
        int add = (t >= o) ? ws[t - o] : 0;
        __syncthreads();
        ws[t] = v + add;
        __syncthreads();
    }
    int pre = (t == 0) ? 0 : ws[t - 1];
    excl[2 * t] = pre;
    excl[2 * t + 1] = pre + hist[2 * t];
    __syncthreads();
    int node0 = b * BWID;
    for (int i = t; i < BWID; i += 256) {
        int node = node0 + i;
        if (node < N_NODES) {
            row_ptr[node] = beg + excl[i];
            dis[node] = rsqrtf((float)(hist[i] + 1));   // +1 = self-loop
        } else if (node == N_NODES) {
            row_ptr[node] = beg + excl[i];
        }
    }
    __syncthreads();
    for (int i = t; i < BWID; i += 256) hist[i] = excl[i];
    __syncthreads();
    for (int i = beg + t; i < end; i += 256) {
        uint p = stage[i];
        int d9 = p & (BWID - 1);
        int r = atomicAdd(&hist[d9], 1);
        col[beg + r] = (int)(p >> BW_LOG);
    }
}

// ---------------- W conversion: split-precision, n-major, all 3 layers ----------------

__global__ void wconv_k(const float* __restrict__ Wa, const float* __restrict__ Wb,
                        const float* __restrict__ Wc, ushort* __restrict__ Whi,
                        ushort* __restrict__ Wlo) {
    int i = blockIdx.x * 256 + threadIdx.x;   // 3*16384
    int layer = i >> 14, r = i & 16383;
    const float* W = layer == 0 ? Wa : (layer == 1 ? Wb : Wc);
    int k = r >> 7, nn = r & 127;
    float w = W[r];
    ushort h = f2bf(w);
    size_t o = (size_t)layer * DIM * DIM + nn * 128 + k;
    Whi[o] = h;
    Wlo[o] = f2bf(w - bf2f(h));
}

// ---------------- MFMA GEMM, split-precision W (and A for fp32 input) ----------------
// Round-2 change: epilogue scales each output row by dis[row] (row scaling commutes
// with GEMM), so aggregation reads pre-normalized H' = dis .* (X @ W) and needs no
// per-edge dis[c] gather.

template <typename TIn>
__global__ __launch_bounds__(256) void gemm_mfma_k(const TIn* __restrict__ X,
                                                   const ushort* __restrict__ Whi,
                                                   const ushort* __restrict__ Wlo,
                                                   const float* __restrict__ dis,
                                                   ushort* __restrict__ H, int n) {
    __shared__ __align__(16) ushort lds[128 * 136];   // 34 KB; re-staged per pass
    int t = threadIdx.x;

    auto stageW = [&](const ushort* Wsw) {
#pragma unroll
        for (int j = 0; j < 8; j++) {
            int idx8 = t + j * 256;              // 2048 octets
            int nn = idx8 >> 4;
            int k0 = (idx8 & 15) * 8;
            uint4 v = ((const uint4*)Wsw)[idx8];
            *(uint4*)&lds[nn * 136 + k0] = v;
        }
    };

    stageW(Whi);

    int w = t >> 6, l = t & 63;
    int quad = l >> 4, lr = l & 15;
    int arow = blockIdx.x * 64 + w * 16 + lr;
    int srow = arow < n ? arow : n - 1;          // clamp: no OOB read

    bf16x8 a[4], alo[4];
#pragma unroll
    for (int q = 0; q < 4; q++) {
        if constexpr (sizeof(TIn) == 4) {
            const float4* xp = (const float4*)(X + (size_t)srow * DIM + q * 32 + quad * 8);
            float4 v0 = xp[0], v1 = xp[1];
            float f[8] = {v0.x, v0.y, v0.z, v0.w, v1.x, v1.y, v1.z, v1.w};
            bf16x8 ah, al;
#pragma unroll
            for (int j = 0; j < 8; j++) {
                ushort h = f2bf(f[j]);
                ah[j] = (short)h;
                al[j] = (short)f2bf(f[j] - bf2f(h));
            }
            a[q] = ah;
            alo[q] = al;
        } else {
            a[q] = *(const bf16x8*)(X + (size_t)srow * DIM + q * 32 + quad * 8);
        }
    }

    f32x4 acc[8];
#pragma unroll
    for (int c = 0; c < 8; c++) acc[c] = (f32x4){0.f, 0.f, 0.f, 0.f};

    __syncthreads();
#pragma unroll
    for (int q = 0; q < 4; q++) {
#pragma unroll
        for (int c = 0; c < 8; c++) {
            bf16x8 b = *(const bf16x8*)&lds[(c * 16 + lr) * 136 + q * 32 + quad * 8];
            acc[c] = __builtin_amdgcn_mfma_f32_16x16x32_bf16(a[q], b, acc[c], 0, 0, 0);
            if constexpr (sizeof(TIn) == 4)
                acc[c] = __builtin_amdgcn_mfma_f32_16x16x32_bf16(alo[q], b, acc[c], 0, 0, 0);
        }
    }

    __syncthreads();
    stageW(Wlo);
    __syncthreads();
#pragma unroll
    for (int q = 0; q < 4; q++) {
#pragma unroll
        for (int c = 0; c < 8; c++) {
            bf16x8 b = *(const bf16x8*)&lds[(c * 16 + lr) * 136 + q * 32 + quad * 8];
            acc[c] = __builtin_amdgcn_mfma_f32_16x16x32_bf16(a[q], b, acc[c], 0, 0, 0);
        }
    }

    // per-output-row dis scale (C/D layout: row = w*16 + quad*4 + r)
    float dsc[4];
    int orow0 = blockIdx.x * 64 + w * 16 + quad * 4;
#pragma unroll
    for (int r = 0; r < 4; r++) {
        int rr = orow0 + r;
        if (rr > n - 1) rr = n - 1;
        dsc[r] = dis[rr];
    }

    __syncthreads();
#pragma unroll
    for (int c = 0; c < 8; c++) {
#pragma unroll
        for (int r = 0; r < 4; r++) {
            int rl = w * 16 + quad * 4 + r;
            lds[rl * 136 + c * 16 + lr] = f2bf(acc[c][r] * dsc[r]);
        }
    }
    __syncthreads();
#pragma unroll
    for (int j = 0; j < 4; j++) {
        int idx = t + j * 256;                   // 1024 slots = 64 rows x 16 uint4
        int rl = idx >> 4, sl = idx & 15;
        int grow = blockIdx.x * 64 + rl;
        if (grow < n) {
            uint4 v = *(const uint4*)&lds[rl * 136 + sl * 8];
            ((uint4*)(H + (size_t)grow * DIM))[sl] = v;
        }
    }
}

// ---------------- CSR aggregation: 16 lanes/node, uint4 gathers ----------------
// Round-2 change: the agg request stream was ~2/3 redundant (col and dis loaded by
// all 16 lanes of a group; dis gathered per edge). Fix: (a) H pre-scaled by dis in
// the GEMM epilogue -> no dis gather, pure adds; (b) block's col slab (16
// consecutive nodes = contiguous CSR range) cooperatively staged into LDS once,
// inner loop reads cols via LDS broadcast. Round-1 lesson: per-wave MLP depth alone
// is NOT the lever (occupancy halved, time flat -> per-CU request-rate bound).

#define COLCAP 1024

#define AGG_STAGE                                                                \
    int first_n = blockIdx.x * 16;                                               \
    int cbase = row_ptr[first_n];                                                \
    int last_n = first_n + 16;                                                   \
    if (last_n > n) last_n = n;                                                  \
    int ccnt = row_ptr[last_n] - cbase;                                          \
    if (ccnt > COLCAP) ccnt = COLCAP;                                            \
    for (int i = threadIdx.x; i < ccnt; i += 256) cols_s[i] = col[cbase + i];    \
    __syncthreads();

#define AGG_EDGE8(E0, PRED)                                                      \
    {                                                                            \
        int c_[8];                                                               \
        float w_[8];                                                             \
        uint4 p_[8];                                                             \
        _Pragma("unroll") for (int j = 0; j < 8; j++) {                          \
            int idx = E0 + j;                                                    \
            w_[j] = 1.f;                                                         \
            if (PRED) {                                                          \
                w_[j] = (idx < end) ? 1.f : 0.f;                                 \
                idx = idx < end ? idx : end - 1;                                 \
            }                                                                    \
            int li = idx - cbase;                                                \
            c_[j] = (li < COLCAP) ? cols_s[li] : col[idx];                       \
        }                                                                        \
        _Pragma("unroll") for (int j = 0; j < 8; j++) {                          \
            p_[j] = *(const uint4*)(Hl + (size_t)c_[j] * DIM);                   \
        }                                                                        \
        _Pragma("unroll") for (int j = 0; j < 8; j++) {                          \
            a0 += w_[j] * bflo(p_[j].x);                                         \
            a1 += w_[j] * bfhi(p_[j].x);                                         \
            a2 += w_[j] * bflo(p_[j].y);                                         \
            a3 += w_[j] * bfhi(p_[j].y);                                         \
            a4 += w_[j] * bflo(p_[j].z);                                         \
            a5 += w_[j] * bfhi(p_[j].z);                                         \
            a6 += w_[j] * bflo(p_[j].w);                                         \
            a7 += w_[j] * bfhi(p_[j].w);                                         \
        }                                                                        \
    }

#define AGG_BODY                                                                 \
    const ushort* Hl = H + lane * 8;                                             \
    float dn = dis[node];                                                        \
    int beg = row_ptr[node], end = row_ptr[node + 1];                            \
    uint4 pw = *(const uint4*)(Hl + (size_t)node * DIM);                         \
    a0 = bflo(pw.x); a1 = bfhi(pw.x);                                            \
    a2 = bflo(pw.y); a3 = bfhi(pw.y);                                            \
    a4 = bflo(pw.z); a5 = bfhi(pw.z);                                            \
    a6 = bflo(pw.w); a7 = bfhi(pw.w);                                            \
    int e = beg;                                                                 \
    for (; e + 7 < end; e += 8) AGG_EDGE8(e, 0)                                  \
    if (e < end) AGG_EDGE8(e, 1)                                                 \
    a0 = fmaxf(a0 * dn + bias[d0], 0.f);                                         \
    a1 = fmaxf(a1 * dn + bias[d0 + 1], 0.f);                                     \
    a2 = fmaxf(a2 * dn + bias[d0 + 2], 0.f);                                     \
    a3 = fmaxf(a3 * dn + bias[d0 + 3], 0.f);                                     \
    a4 = fmaxf(a4 * dn + bias[d0 + 4], 0.f);                                     \
    a5 = fmaxf(a5 * dn + bias[d0 + 5], 0.f);                                     \
    a6 = fmaxf(a6 * dn + bias[d0 + 6], 0.f);                                     \
    a7 = fmaxf(a7 * dn + bias[d0 + 7], 0.f);

__global__ __launch_bounds__(256) void agg_k(const ushort* __restrict__ H,
                                             const int* __restrict__ row_ptr,
                                             const int* __restrict__ col,
                                             const float* __restrict__ dis,
                                             const float* __restrict__ bias,
                                             ushort* __restrict__ Out, int n) {
    __shared__ int cols_s[COLCAP];
    int node = blockIdx.x * 16 + (threadIdx.x >> 4);
    int lane = threadIdx.x & 15;
    AGG_STAGE
    if (node >= n) return;
    int d0 = lane * 8;
    float a0, a1, a2, a3, a4, a5, a6, a7;
    AGG_BODY
    uint4 o;
    o.x = (uint)f2bf(a0) | ((uint)f2bf(a1) << 16);
    o.y = (uint)f2bf(a2) | ((uint)f2bf(a3) << 16);
    o.z = (uint)f2bf(a4) | ((uint)f2bf(a5) << 16);
    o.w = (uint)f2bf(a6) | ((uint)f2bf(a7) << 16);
    *(uint4*)(Out + (size_t)node * DIM + d0) = o;
}

// layer-3 agg fused with global_add_pool: LDS run-reduction over sorted batch ids,
// one global atomic per (run x feature). Final h never rounded to bf16.
// (Round-14 lesson: per-wave GLOBAL atomic fan-out explodes write traffic —
//  keep the block-level LDS funnel.)
__global__ __launch_bounds__(256) void agg_pool_k(const ushort* __restrict__ H,
                                                  const int* __restrict__ row_ptr,
                                                  const int* __restrict__ col,
                                                  const float* __restrict__ dis,
                                                  const float* __restrict__ bias,
                                                  const int* __restrict__ batch,
                                                  float* __restrict__ Out, int n) {
    __shared__ float acc[DIM];
    __shared__ int cols_s[COLCAP];
    int t = threadIdx.x;
    int node = blockIdx.x * 16 + (t >> 4);
    int lane = t & 15;
    int d0 = lane * 8;
    float a0 = 0.f, a1 = 0.f, a2 = 0.f, a3 = 0.f, a4 = 0.f, a5 = 0.f, a6 = 0.f, a7 = 0.f;
    AGG_STAGE
    int g = -1;
    if (node < n) {
        AGG_BODY
        g = batch[node];
    }
    int first = blockIdx.x * 16;                       // always < n (grid = ceil(n/16))
    int last = first + 15 < n ? first + 15 : n - 1;
    int g0 = batch[first], g1 = batch[last];
    for (int gr = g0; gr <= g1; gr++) {
        if (t < DIM) acc[t] = 0.f;
        __syncthreads();
        if (g == gr) {
            atomicAdd(&acc[d0], a0);
            atomicAdd(&acc[d0 + 1], a1);
            atomicAdd(&acc[d0 + 2], a2);
            atomicAdd(&acc[d0 + 3], a3);
            atomicAdd(&acc[d0 + 4], a4);
            atomicAdd(&acc[d0 + 5], a5);
            atomicAdd(&acc[d0 + 6], a6);
            atomicAdd(&acc[d0 + 7], a7);
        }
        __syncthreads();
        if (t < DIM) atomicAdd(&Out[gr * DIM + t], acc[t]);
        __syncthreads();
    }
}

// ---------------- launch ----------------

extern "C" void kernel_launch(void* const* d_in, const int* in_sizes, int n_in,
                              void* d_out, int out_size, void* d_ws, size_t ws_size,
                              hipStream_t stream) {
    const float* x  = (const float*)d_in[0];
    const float* W1 = (const float*)d_in[1];
    const float* b1 = (const float*)d_in[2];
    const float* W2 = (const float*)d_in[3];
    const float* b2 = (const float*)d_in[4];
    const float* W3 = (const float*)d_in[5];
    const float* b3 = (const float*)d_in[6];
    const int*   ei = (const int*)d_in[7];
    const int*   bv = (const int*)d_in[8];
    float* out = (float*)d_out;

    const int N = N_NODES, E = N_EDGES;

    char* p = (char*)d_ws;
    auto alloc = [&](size_t bytes) -> void* {
        void* r = (void*)p;
        p += (bytes + 255) & ~(size_t)255;
        return r;
    };
    int*    bcnt_pad = (int*)alloc((size_t)NB * 16 * 4);
    int*    bcur_pad = (int*)alloc((size_t)NB * 16 * 4);
    int*    bbase    = (int*)alloc((size_t)(NB + 1) * 4);
    int*    row_ptr  = (int*)alloc((size_t)(N + 1) * 4);
    float*  dis      = (float*)alloc((size_t)N * 4);
    uint*   stage    = (uint*)alloc((size_t)E * 4);
    int*    col      = (int*)alloc((size_t)E * 4);
    ushort* B1       = (ushort*)alloc((size_t)N_PAD * DIM * 2);
    ushort* B2       = (ushort*)alloc((size_t)N_PAD * DIM * 2);

    // W buffers overlaid on stage (dead after csr_k; wconv runs after it in-stream)
    ushort* Whi = (ushort*)stage;                        // 3 * 16384
    ushort* Wlo = Whi + (size_t)3 * DIM * DIM;

    const int* src = ei;
    const int* dst = ei + E;

    hipMemsetAsync(d_out, 0, (size_t)N_GRAPHS * DIM * sizeof(float), stream);
    hipMemsetAsync(bcnt_pad, 0, (size_t)NB * 16 * 4, stream);

    bhist_k<<<NCHUNK, 256, 0, stream>>>(dst, bcnt_pad, E);
    bscan_k<<<1, 128, 0, stream>>>(bcnt_pad, bbase, bcur_pad);
    bscat_k<<<NCHUNK, 256, 0, stream>>>(src, dst, bcur_pad, stage, E);
    csr_k<<<NB, 256, 0, stream>>>(stage, bbase, row_ptr, dis, col);

    wconv_k<<<192, 256, 0, stream>>>(W1, W2, W3, Whi, Wlo);

    int gemm_grid = N_PAD / 64;          // 782
    int agg_grid  = (N + 15) / 16;

    gemm_mfma_k<float><<<gemm_grid, 256, 0, stream>>>(x, Whi, Wlo, dis, B1, N);
    agg_k<<<agg_grid, 256, 0, stream>>>(B1, row_ptr, col, dis, b1, B2, N);

    gemm_mfma_k<ushort><<<gemm_grid, 256, 0, stream>>>(B2, Whi + (size_t)DIM * DIM,
                                                       Wlo + (size_t)DIM * DIM, dis, B1, N);
    agg_k<<<agg_grid, 256, 0, stream>>>(B1, row_ptr, col, dis, b2, B2, N);

    gemm_mfma_k<ushort><<<gemm_grid, 256, 0, stream>>>(B2, Whi + (size_t)2 * DIM * DIM,
                                                       Wlo + (size_t)2 * DIM * DIM, dis, B1, N);
    agg_pool_k<<<agg_grid, 256, 0, stream>>>(B1, row_ptr, col, dis, b3, bv, out, N);
}

// Round 3
// 285.661 us; speedup vs baseline: 1.0133x; 1.0133x over previous
//
#include <hip/hip_runtime.h>

#define N_NODES 50000
#define N_EDGES 800000
#define N_GRAPHS 512
#define DIM 128
#define N_PAD 50048

#define BW_LOG 9
#define BWID 512                                  // nodes per bucket
#define NB ((N_NODES + BWID - 1) / BWID)          // 98
#define CHUNK 4096                                // edges per phase-A block
#define NCHUNK ((N_EDGES + CHUNK - 1) / CHUNK)    // 196

// quarter-major H layout: Hq[q][node][32 features]  (3.2 MB per quarter -> fits 4MB XCD L2)
#define QOFF(q) ((size_t)(q) * N_PAD * 32)

typedef unsigned int uint;
typedef unsigned short ushort;
typedef __attribute__((ext_vector_type(8))) short bf16x8;
typedef __attribute__((ext_vector_type(4))) float f32x4;

// bf16 helpers (RNE pack, cheap unpack)
__device__ __forceinline__ ushort f2bf(float f) {
    uint u = __float_as_uint(f);
    return (ushort)((u + 0x7fffu + ((u >> 16) & 1u)) >> 16);
}
__device__ __forceinline__ float bf2f(ushort h) { return __uint_as_float((uint)h << 16); }
__device__ __forceinline__ float bflo(uint p) { return __uint_as_float(p << 16); }
__device__ __forceinline__ float bfhi(uint p) { return __uint_as_float(p & 0xffff0000u); }

// ---------------- CSR build: bucket-sorted ----------------

__global__ __launch_bounds__(256) void bhist_k(const int* __restrict__ dst,
                                               int* __restrict__ bcnt_pad, int e) {
    __shared__ int h[NB];
    int t = threadIdx.x;
    for (int i = t; i < NB; i += 256) h[i] = 0;
    __syncthreads();
    int base = blockIdx.x * CHUNK;
    for (int i = t; i < CHUNK; i += 256) {
        int idx = base + i;
        if (idx < e) atomicAdd(&h[dst[idx] >> BW_LOG], 1);
    }
    __syncthreads();
    for (int i = t; i < NB; i += 256)
        if (h[i]) atomicAdd(&bcnt_pad[i << 4], h[i]);
}

// parallel 98-wide exclusive scan (one 128-thread block)
__global__ void bscan_k(const int* __restrict__ bcnt_pad, int* __restrict__ bbase,
                        int* __restrict__ bcur_pad) {
    __shared__ int v[128];
    int t = threadIdx.x;
    int x = (t < NB) ? bcnt_pad[t << 4] : 0;
    v[t] = x;
    __syncthreads();
    for (int o = 1; o < 128; o <<= 1) {
        int val = v[t];
        int add = (t >= o) ? v[t - o] : 0;
        __syncthreads();
        v[t] = val + add;
        __syncthreads();
    }
    if (t < NB) {
        int excl = (t == 0) ? 0 : v[t - 1];
        bbase[t] = excl;
        bcur_pad[t << 4] = excl;
    }
    if (t == NB - 1) bbase[NB] = v[t];
}

// packed record: (src << 9) | (dst & 511)
__global__ __launch_bounds__(256) void bscat_k(const int* __restrict__ src,
                                               const int* __restrict__ dst,
                                               int* __restrict__ bcur_pad,
                                               uint* __restrict__ stage, int e) {
    __shared__ int h[NB];
    __shared__ int bb[NB];
    __shared__ int lc[NB];
    int t = threadIdx.x;
    for (int i = t; i < NB; i += 256) h[i] = 0;
    __syncthreads();
    int base = blockIdx.x * CHUNK;
    for (int i = t; i < CHUNK; i += 256) {
        int idx = base + i;
        if (idx < e) atomicAdd(&h[dst[idx] >> BW_LOG], 1);
    }
    __syncthreads();
    for (int i = t; i < NB; i += 256) {
        int c = h[i];
        bb[i] = c ? atomicAdd(&bcur_pad[i << 4], c) : 0;
        lc[i] = 0;
    }
    __syncthreads();
    for (int i = t; i < CHUNK; i += 256) {
        int idx = base + i;
        if (idx < e) {
            int d = dst[idx];
            int b = d >> BW_LOG;
            int r = atomicAdd(&lc[b], 1);
            stage[bb[b] + r] = ((uint)src[idx] << BW_LOG) | (uint)(d & (BWID - 1));
        }
    }
}

__global__ __launch_bounds__(256) void csr_k(const uint* __restrict__ stage,
                                             const int* __restrict__ bbase,
                                             int* __restrict__ row_ptr,
                                             float* __restrict__ dis,
                                             int* __restrict__ col) {
    __shared__ int hist[BWID];
    __shared__ int excl[BWID];
    __shared__ int ws[256];
    int b = blockIdx.x, t = threadIdx.x;
    int beg = bbase[b], end = bbase[b + 1];
    for (int i = t; i < BWID; i += 256) hist[i] = 0;
    __syncthreads();
    for (int i = beg + t; i < end; i += 256)
        atomicAdd(&hist[stage[i] & (BWID - 1)], 1);
    __syncthreads();
    int s = hist[2 * t] + hist[2 * t + 1];
    ws[t] = s;
    __syncthreads();
    for (int o = 1; o < 256; o <<= 1) {
        int v = ws[t];
        int add = (t >= o) ? ws[t - o] : 0;
        __syncthreads();
        ws[t] = v + add;
        __syncthreads();
    }
    int pre = (t == 0) ? 0 : ws[t - 1];
    excl[2 * t] = pre;
    excl[2 * t + 1] = pre + hist[2 * t];
    __syncthreads();
    int node0 = b * BWID;
    for (int i = t; i < BWID; i += 256) {
        int node = node0 + i;
        if (node < N_NODES) {
            row_ptr[node] = beg + excl[i];
            dis[node] = rsqrtf((float)(hist[i] + 1));   // +1 = self-loop
        } else if (node == N_NODES) {
            row_ptr[node] = beg + excl[i];
        }
    }
    __syncthreads();
    for (int i = t; i < BWID; i += 256) hist[i] = excl[i];
    __syncthreads();
    for (int i = beg + t; i < end; i += 256) {
        uint p = stage[i];
        int d9 = p & (BWID - 1);
        int r = atomicAdd(&hist[d9], 1);
        col[beg + r] = (int)(p >> BW_LOG);
    }
}

// ---------------- W conversion: split-precision, n-major, all 3 layers ----------------

__global__ void wconv_k(const float* __restrict__ Wa, const float* __restrict__ Wb,
                        const float* __restrict__ Wc, ushort* __restrict__ Whi,
                        ushort* __restrict__ Wlo) {
    int i = blockIdx.x * 256 + threadIdx.x;   // 3*16384
    int layer = i >> 14, r = i & 16383;
    const float* W = layer == 0 ? Wa : (layer == 1 ? Wb : Wc);
    int k = r >> 7, nn = r & 127;
    float w = W[r];
    ushort h = f2bf(w);
    size_t o = (size_t)layer * DIM * DIM + nn * 128 + k;
    Whi[o] = h;
    Wlo[o] = f2bf(w - bf2f(h));
}

// ---------------- MFMA GEMM, split-precision W (and A for fp32 input) ----------------
// H is stored/read quarter-major (QOFF). Epilogue scales each output row by dis[row]
// (row scaling commutes with GEMM), so aggregation reads pre-normalized rows.

template <typename TIn>
__global__ __launch_bounds__(256) void gemm_mfma_k(const TIn* __restrict__ X,
                                                   const ushort* __restrict__ Whi,
                                                   const ushort* __restrict__ Wlo,
                                                   const float* __restrict__ dis,
                                                   ushort* __restrict__ H, int n) {
    __shared__ __align__(16) ushort lds[128 * 136];   // 34 KB; re-staged per pass
    int t = threadIdx.x;

    auto stageW = [&](const ushort* Wsw) {
#pragma unroll
        for (int j = 0; j < 8; j++) {
            int idx8 = t + j * 256;              // 2048 octets
            int nn = idx8 >> 4;
            int k0 = (idx8 & 15) * 8;
            uint4 v = ((const uint4*)Wsw)[idx8];
            *(uint4*)&lds[nn * 136 + k0] = v;
        }
    };

    stageW(Whi);

    int w = t >> 6, l = t & 63;
    int quad = l >> 4, lr = l & 15;
    int arow = blockIdx.x * 64 + w * 16 + lr;
    int srow = arow < n ? arow : n - 1;          // clamp: no OOB read

    bf16x8 a[4], alo[4];
#pragma unroll
    for (int q = 0; q < 4; q++) {
        if constexpr (sizeof(TIn) == 4) {
            const float4* xp = (const float4*)(X + (size_t)srow * DIM + q * 32 + quad * 8);
            float4 v0 = xp[0], v1 = xp[1];
            float f[8] = {v0.x, v0.y, v0.z, v0.w, v1.x, v1.y, v1.z, v1.w};
            bf16x8 ah, al;
#pragma unroll
            for (int j = 0; j < 8; j++) {
                ushort h = f2bf(f[j]);
                ah[j] = (short)h;
                al[j] = (short)f2bf(f[j] - bf2f(h));
            }
            a[q] = ah;
            alo[q] = al;
        } else {
            // quarter-major bf16 input
            a[q] = *(const bf16x8*)(X + QOFF(q) + (size_t)srow * 32 + quad * 8);
        }
    }

    f32x4 acc[8];
#pragma unroll
    for (int c = 0; c < 8; c++) acc[c] = (f32x4){0.f, 0.f, 0.f, 0.f};

    __syncthreads();
#pragma unroll
    for (int q = 0; q < 4; q++) {
#pragma unroll
        for (int c = 0; c < 8; c++) {
            bf16x8 b = *(const bf16x8*)&lds[(c * 16 + lr) * 136 + q * 32 + quad * 8];
            acc[c] = __builtin_amdgcn_mfma_f32_16x16x32_bf16(a[q], b, acc[c], 0, 0, 0);
            if constexpr (sizeof(TIn) == 4)
                acc[c] = __builtin_amdgcn_mfma_f32_16x16x32_bf16(alo[q], b, acc[c], 0, 0, 0);
        }
    }

    __syncthreads();
    stageW(Wlo);
    __syncthreads();
#pragma unroll
    for (int q = 0; q < 4; q++) {
#pragma unroll
        for (int c = 0; c < 8; c++) {
            bf16x8 b = *(const bf16x8*)&lds[(c * 16 + lr) * 136 + q * 32 + quad * 8];
            acc[c] = __builtin_amdgcn_mfma_f32_16x16x32_bf16(a[q], b, acc[c], 0, 0, 0);
        }
    }

    // per-output-row dis scale (C/D layout: row = w*16 + quad*4 + r)
    float dsc[4];
    int orow0 = blockIdx.x * 64 + w * 16 + quad * 4;
#pragma unroll
    for (int r = 0; r < 4; r++) {
        int rr = orow0 + r;
        if (rr > n - 1) rr = n - 1;
        dsc[r] = dis[rr];
    }

    __syncthreads();
#pragma unroll
    for (int c = 0; c < 8; c++) {
#pragma unroll
        for (int r = 0; r < 4; r++) {
            int rl = w * 16 + quad * 4 + r;
            lds[rl * 136 + c * 16 + lr] = f2bf(acc[c][r] * dsc[r]);
        }
    }
    __syncthreads();
#pragma unroll
    for (int j = 0; j < 4; j++) {
        int idx = t + j * 256;                   // 1024 slots = 64 rows x 16 uint4
        int rl = idx >> 4, sl = idx & 15;
        int grow = blockIdx.x * 64 + rl;
        if (grow < n) {
            uint4 v = *(const uint4*)&lds[rl * 136 + sl * 8];
            // quarter-major store: slot sl -> quarter sl>>2, sub-slot sl&3
            *(uint4*)(H + QOFF(sl >> 2) + (size_t)grow * 32 + (sl & 3) * 8) = v;
        }
    }
}

// ---------------- CSR aggregation: quarter-split, 4 lanes/node ----------------
// Round-3 change: R1 (ILP) and R2 (request-count) both null -> gather is
// L2-miss-latency bound (working set 12.8MB vs 4MB XCD L2; FETCH 78MB = 6x H).
// Fix: feature-quarter split. Each sub-pass (blockIdx.y = q, dispatched x-major so
// quarters roughly serialize) gathers only Hq[q] = 3.2MB -> L2-resident -> ~200cy
// hits. 4 lanes/node x 16B = 64B/row-quarter; wave has 16 nodes x 8 edges = 128
// rows in flight (4x R2).

#define AGG_EDGE8(E0, PRED)                                                      \
    {                                                                            \
        int c_[8];                                                               \
        float w_[8];                                                             \
        uint4 p_[8];                                                             \
        _Pragma("unroll") for (int j = 0; j < 8; j++) {                          \
            int idx = E0 + j;                                                    \
            w_[j] = 1.f;                                                         \
            if (PRED) {                                                          \
                w_[j] = (idx < end) ? 1.f : 0.f;                                 \
                idx = idx < end ? idx : end - 1;                                 \
            }                                                                    \
            c_[j] = col[idx];                                                    \
        }                                                                        \
        _Pragma("unroll") for (int j = 0; j < 8; j++) {                          \
            p_[j] = *(const uint4*)(Hl + (size_t)c_[j] * 32);                    \
        }                                                                        \
        _Pragma("unroll") for (int j = 0; j < 8; j++) {                          \
            a0 += w_[j] * bflo(p_[j].x);                                         \
            a1 += w_[j] * bfhi(p_[j].x);                                         \
            a2 += w_[j] * bflo(p_[j].y);                                         \
            a3 += w_[j] * bfhi(p_[j].y);                                         \
            a4 += w_[j] * bflo(p_[j].z);                                         \
            a5 += w_[j] * bfhi(p_[j].z);                                         \
            a6 += w_[j] * bflo(p_[j].w);                                         \
            a7 += w_[j] * bfhi(p_[j].w);                                         \
        }                                                                        \
    }

#define AGG_BODY                                                                 \
    const ushort* Hl = H + QOFF(q) + d0l;                                        \
    float dn = dis[node];                                                        \
    int beg = row_ptr[node], end = row_ptr[node + 1];                            \
    uint4 pw = *(const uint4*)(Hl + (size_t)node * 32);                          \
    a0 = bflo(pw.x); a1 = bfhi(pw.x);                                            \
    a2 = bflo(pw.y); a3 = bfhi(pw.y);                                            \
    a4 = bflo(pw.z); a5 = bfhi(pw.z);                                            \
    a6 = bflo(pw.w); a7 = bfhi(pw.w);                                            \
    int e = beg;                                                                 \
    for (; e + 7 < end; e += 8) AGG_EDGE8(e, 0)                                  \
    if (e < end) AGG_EDGE8(e, 1)                                                 \
    a0 = fmaxf(a0 * dn + bias[q * 32 + d0l + 0], 0.f);                           \
    a1 = fmaxf(a1 * dn + bias[q * 32 + d0l + 1], 0.f);                           \
    a2 = fmaxf(a2 * dn + bias[q * 32 + d0l + 2], 0.f);                           \
    a3 = fmaxf(a3 * dn + bias[q * 32 + d0l + 3], 0.f);                           \
    a4 = fmaxf(a4 * dn + bias[q * 32 + d0l + 4], 0.f);                           \
    a5 = fmaxf(a5 * dn + bias[q * 32 + d0l + 5], 0.f);                           \
    a6 = fmaxf(a6 * dn + bias[q * 32 + d0l + 6], 0.f);                           \
    a7 = fmaxf(a7 * dn + bias[q * 32 + d0l + 7], 0.f);

__global__ __launch_bounds__(256) void agg_k(const ushort* __restrict__ H,
                                             const int* __restrict__ row_ptr,
                                             const int* __restrict__ col,
                                             const float* __restrict__ dis,
                                             const float* __restrict__ bias,
                                             ushort* __restrict__ Out, int n) {
    int q = blockIdx.y;
    int t = threadIdx.x;
    int node = blockIdx.x * 64 + (t >> 2);
    int lane = t & 3;
    if (node >= n) return;
    int d0l = lane * 8;
    float a0, a1, a2, a3, a4, a5, a6, a7;
    AGG_BODY
    uint4 o;
    o.x = (uint)f2bf(a0) | ((uint)f2bf(a1) << 16);
    o.y = (uint)f2bf(a2) | ((uint)f2bf(a3) << 16);
    o.z = (uint)f2bf(a4) | ((uint)f2bf(a5) << 16);
    o.w = (uint)f2bf(a6) | ((uint)f2bf(a7) << 16);
    *(uint4*)(Out + QOFF(q) + (size_t)node * 32 + d0l) = o;
}

// layer-3 agg fused with global_add_pool: LDS run-reduction over sorted batch ids,
// one global atomic per (run x quarter-feature). Final h never rounded to bf16.
__global__ __launch_bounds__(256) void agg_pool_k(const ushort* __restrict__ H,
                                                  const int* __restrict__ row_ptr,
                                                  const int* __restrict__ col,
                                                  const float* __restrict__ dis,
                                                  const float* __restrict__ bias,
                                                  const int* __restrict__ batch,
                                                  float* __restrict__ Out, int n) {
    __shared__ float acc[32];
    int q = blockIdx.y;
    int t = threadIdx.x;
    int node = blockIdx.x * 64 + (t >> 2);
    int lane = t & 3;
    int d0l = lane * 8;
    float a0 = 0.f, a1 = 0.f, a2 = 0.f, a3 = 0.f, a4 = 0.f, a5 = 0.f, a6 = 0.f, a7 = 0.f;
    int g = -1;
    if (node < n) {
        AGG_BODY
        g = batch[node];
    }
    int first = blockIdx.x * 64;                       // always < n (grid = ceil(n/64))
    int last = first + 63 < n ? first + 63 : n - 1;
    int g0 = batch[first], g1 = batch[last];
    for (int gr = g0; gr <= g1; gr++) {
        if (t < 32) acc[t] = 0.f;
        __syncthreads();
        if (g == gr) {
            atomicAdd(&acc[d0l], a0);
            atomicAdd(&acc[d0l + 1], a1);
            atomicAdd(&acc[d0l + 2], a2);
            atomicAdd(&acc[d0l + 3], a3);
            atomicAdd(&acc[d0l + 4], a4);
            atomicAdd(&acc[d0l + 5], a5);
            atomicAdd(&acc[d0l + 6], a6);
            atomicAdd(&acc[d0l + 7], a7);
        }
        __syncthreads();
        if (t < 32) atomicAdd(&Out[gr * DIM + q * 32 + t], acc[t]);
        __syncthreads();
    }
}

// ---------------- launch ----------------

extern "C" void kernel_launch(void* const* d_in, const int* in_sizes, int n_in,
                              void* d_out, int out_size, void* d_ws, size_t ws_size,
                              hipStream_t stream) {
    const float* x  = (const float*)d_in[0];
    const float* W1 = (const float*)d_in[1];
    const float* b1 = (const float*)d_in[2];
    const float* W2 = (const float*)d_in[3];
    const float* b2 = (const float*)d_in[4];
    const float* W3 = (const float*)d_in[5];
    const float* b3 = (const float*)d_in[6];
    const int*   ei = (const int*)d_in[7];
    const int*   bv = (const int*)d_in[8];
    float* out = (float*)d_out;

    const int N = N_NODES, E = N_EDGES;

    char* p = (char*)d_ws;
    auto alloc = [&](size_t bytes) -> void* {
        void* r = (void*)p;
        p += (bytes + 255) & ~(size_t)255;
        return r;
    };
    int*    bcnt_pad = (int*)alloc((size_t)NB * 16 * 4);
    int*    bcur_pad = (int*)alloc((size_t)NB * 16 * 4);
    int*    bbase    = (int*)alloc((size_t)(NB + 1) * 4);
    int*    row_ptr  = (int*)alloc((size_t)(N + 1) * 4);
    float*  dis      = (float*)alloc((size_t)N * 4);
    uint*   stage    = (uint*)alloc((size_t)E * 4);
    int*    col      = (int*)alloc((size_t)E * 4);
    ushort* B1       = (ushort*)alloc((size_t)N_PAD * DIM * 2);
    ushort* B2       = (ushort*)alloc((size_t)N_PAD * DIM * 2);

    // W buffers overlaid on stage (dead after csr_k; wconv runs after it in-stream)
    ushort* Whi = (ushort*)stage;                        // 3 * 16384
    ushort* Wlo = Whi + (size_t)3 * DIM * DIM;

    const int* src = ei;
    const int* dst = ei + E;

    hipMemsetAsync(d_out, 0, (size_t)N_GRAPHS * DIM * sizeof(float), stream);
    hipMemsetAsync(bcnt_pad, 0, (size_t)NB * 16 * 4, stream);

    bhist_k<<<NCHUNK, 256, 0, stream>>>(dst, bcnt_pad, E);
    bscan_k<<<1, 128, 0, stream>>>(bcnt_pad, bbase, bcur_pad);
    bscat_k<<<NCHUNK, 256, 0, stream>>>(src, dst, bcur_pad, stage, E);
    csr_k<<<NB, 256, 0, stream>>>(stage, bbase, row_ptr, dis, col);

    wconv_k<<<192, 256, 0, stream>>>(W1, W2, W3, Whi, Wlo);

    int gemm_grid = N_PAD / 64;          // 782
    dim3 agg_grid((N + 63) / 64, 4);     // x = node blocks, y = feature quarter

    gemm_mfma_k<float><<<gemm_grid, 256, 0, stream>>>(x, Whi, Wlo, dis, B1, N);
    agg_k<<<agg_grid, 256, 0, stream>>>(B1, row_ptr, col, dis, b1, B2, N);

    gemm_mfma_k<ushort><<<gemm_grid, 256, 0, stream>>>(B2, Whi + (size_t)DIM * DIM,
                                                       Wlo + (size_t)DIM * DIM, dis, B1, N);
    agg_k<<<agg_grid, 256, 0, stream>>>(B1, row_ptr, col, dis, b2, B2, N);

    gemm_mfma_k<ushort><<<gemm_grid, 256, 0, stream>>>(B2, Whi + (size_t)2 * DIM * DIM,
                                                       Wlo + (size_t)2 * DIM * DIM, dis, B1, N);
    agg_pool_k<<<agg_grid, 256, 0, stream>>>(B1, row_ptr, col, dis, b3, bv, out, N);
}

// Round 4
// 273.925 us; speedup vs baseline: 1.0567x; 1.0428x over previous
//
#include <hip/hip_runtime.h>

#define N_NODES 50000
#define N_EDGES 800000
#define N_GRAPHS 512
#define DIM 128
#define N_PAD 50048

#define BW_LOG 9
#define BWID 512                                  // nodes per bucket
#define NB ((N_NODES + BWID - 1) / BWID)          // 98
#define CHUNK 4096                                // edges per phase-A block
#define NCHUNK ((N_EDGES + CHUNK - 1) / CHUNK)    // 196

typedef unsigned int uint;
typedef unsigned short ushort;
typedef __attribute__((ext_vector_type(8))) short bf16x8;
typedef __attribute__((ext_vector_type(4))) float f32x4;

// bf16 helpers (RNE pack, cheap unpack)
__device__ __forceinline__ ushort f2bf(float f) {
    uint u = __float_as_uint(f);
    return (ushort)((u + 0x7fffu + ((u >> 16) & 1u)) >> 16);
}
__device__ __forceinline__ float bf2f(ushort h) { return __uint_as_float((uint)h << 16); }
__device__ __forceinline__ float bflo(uint p) { return __uint_as_float(p << 16); }
__device__ __forceinline__ float bfhi(uint p) { return __uint_as_float(p & 0xffff0000u); }

// ---------------- CSR build phase A: bucket histogram (+ independent wconv) -------
// Blocks < NCHUNK: histogram dst into 98 buckets. Blocks >= NCHUNK: convert W1/2/3
// to split-precision n-major bf16 (independent work, overlapped here to save a
// launch; W lives in its own workspace since stage is still live).

__global__ __launch_bounds__(256) void bhist_wconv_k(const int* __restrict__ dst,
                                                     int* __restrict__ bcnt_pad, int e,
                                                     const float* __restrict__ Wa,
                                                     const float* __restrict__ Wb,
                                                     const float* __restrict__ Wc,
                                                     ushort* __restrict__ Whi,
                                                     ushort* __restrict__ Wlo) {
    int t = threadIdx.x;
    if (blockIdx.x < NCHUNK) {
        __shared__ int h[NB];
        for (int i = t; i < NB; i += 256) h[i] = 0;
        __syncthreads();
        int base = blockIdx.x * CHUNK;
        for (int i = t; i < CHUNK; i += 256) {
            int idx = base + i;
            if (idx < e) atomicAdd(&h[dst[idx] >> BW_LOG], 1);
        }
        __syncthreads();
        for (int i = t; i < NB; i += 256)
            if (h[i]) atomicAdd(&bcnt_pad[i << 4], h[i]);
        return;
    }
    int i = (blockIdx.x - NCHUNK) * 256 + t;      // 3*16384
    int layer = i >> 14, r = i & 16383;
    const float* W = layer == 0 ? Wa : (layer == 1 ? Wb : Wc);
    int k = r >> 7, nn = r & 127;
    float w = W[r];
    ushort h = f2bf(w);
    size_t o = (size_t)layer * DIM * DIM + nn * 128 + k;
    Whi[o] = h;
    Wlo[o] = f2bf(w - bf2f(h));
}

// parallel 98-wide exclusive scan (one 128-thread block)
__global__ void bscan_k(const int* __restrict__ bcnt_pad, int* __restrict__ bbase,
                        int* __restrict__ bcur_pad) {
    __shared__ int v[128];
    int t = threadIdx.x;
    int x = (t < NB) ? bcnt_pad[t << 4] : 0;
    v[t] = x;
    __syncthreads();
    for (int o = 1; o < 128; o <<= 1) {
        int val = v[t];
        int add = (t >= o) ? v[t - o] : 0;
        __syncthreads();
        v[t] = val + add;
        __syncthreads();
    }
    if (t < NB) {
        int excl = (t == 0) ? 0 : v[t - 1];
        bbase[t] = excl;
        bcur_pad[t << 4] = excl;
    }
    if (t == NB - 1) bbase[NB] = v[t];
}

// ---------------- bscat overlapped with gemm1 ----------------
// Blocks < NCHUNK: scatter packed edge records (src<<9 | dst&511) into bucket-sorted
// stage. Blocks >= NCHUNK: gemm1 = bf16(X @ W1), split-precision A and W, RAW output
// (no dis fold — dis isn't ready yet; layer-1 agg applies dis[c] per edge instead,
// which R2 showed costs ~nothing: same-address-per-group loads dedup in the TA).

__global__ __launch_bounds__(256) void bscat_gemm1_k(const int* __restrict__ src,
                                                     const int* __restrict__ dst,
                                                     int* __restrict__ bcur_pad,
                                                     uint* __restrict__ stage, int e,
                                                     const float* __restrict__ X,
                                                     const ushort* __restrict__ Whi,
                                                     const ushort* __restrict__ Wlo,
                                                     ushort* __restrict__ H, int n) {
    __shared__ __align__(16) ushort smem[128 * 136];   // 34.8 KB, dual-use
    int t = threadIdx.x;

    if (blockIdx.x < NCHUNK) {
        int* h  = (int*)smem;
        int* bb = h + NB;
        int* lc = bb + NB;
        for (int i = t; i < NB; i += 256) h[i] = 0;
        __syncthreads();
        int base = blockIdx.x * CHUNK;
        for (int i = t; i < CHUNK; i += 256) {
            int idx = base + i;
            if (idx < e) atomicAdd(&h[dst[idx] >> BW_LOG], 1);
        }
        __syncthreads();
        for (int i = t; i < NB; i += 256) {
            int c = h[i];
            bb[i] = c ? atomicAdd(&bcur_pad[i << 4], c) : 0;
            lc[i] = 0;
        }
        __syncthreads();
        for (int i = t; i < CHUNK; i += 256) {
            int idx = base + i;
            if (idx < e) {
                int d = dst[idx];
                int b = d >> BW_LOG;
                int r = atomicAdd(&lc[b], 1);
                stage[bb[b] + r] = ((uint)src[idx] << BW_LOG) | (uint)(d & (BWID - 1));
            }
        }
        return;
    }

    // ---- gemm1 ----
    ushort* lds = smem;
    int gb = blockIdx.x - NCHUNK;
    auto stageW = [&](const ushort* Wsw) {
#pragma unroll
        for (int j = 0; j < 8; j++) {
            int idx8 = t + j * 256;
            int nn = idx8 >> 4;
            int k0 = (idx8 & 15) * 8;
            uint4 v = ((const uint4*)Wsw)[idx8];
            *(uint4*)&lds[nn * 136 + k0] = v;
        }
    };
    stageW(Whi);

    int w = t >> 6, l = t & 63;
    int quad = l >> 4, lr = l & 15;
    int arow = gb * 64 + w * 16 + lr;
    int srow = arow < n ? arow : n - 1;

    bf16x8 a[4], alo[4];
#pragma unroll
    for (int q = 0; q < 4; q++) {
        const float4* xp = (const float4*)(X + (size_t)srow * DIM + q * 32 + quad * 8);
        float4 v0 = xp[0], v1 = xp[1];
        float f[8] = {v0.x, v0.y, v0.z, v0.w, v1.x, v1.y, v1.z, v1.w};
        bf16x8 ah, al;
#pragma unroll
        for (int j = 0; j < 8; j++) {
            ushort hh = f2bf(f[j]);
            ah[j] = (short)hh;
            al[j] = (short)f2bf(f[j] - bf2f(hh));
        }
        a[q] = ah;
        alo[q] = al;
    }

    f32x4 acc[8];
#pragma unroll
    for (int c = 0; c < 8; c++) acc[c] = (f32x4){0.f, 0.f, 0.f, 0.f};

    __syncthreads();
#pragma unroll
    for (int q = 0; q < 4; q++) {
#pragma unroll
        for (int c = 0; c < 8; c++) {
            bf16x8 b = *(const bf16x8*)&lds[(c * 16 + lr) * 136 + q * 32 + quad * 8];
            acc[c] = __builtin_amdgcn_mfma_f32_16x16x32_bf16(a[q], b, acc[c], 0, 0, 0);
            acc[c] = __builtin_amdgcn_mfma_f32_16x16x32_bf16(alo[q], b, acc[c], 0, 0, 0);
        }
    }
    __syncthreads();
    stageW(Wlo);
    __syncthreads();
#pragma unroll
    for (int q = 0; q < 4; q++) {
#pragma unroll
        for (int c = 0; c < 8; c++) {
            bf16x8 b = *(const bf16x8*)&lds[(c * 16 + lr) * 136 + q * 32 + quad * 8];
            acc[c] = __builtin_amdgcn_mfma_f32_16x16x32_bf16(a[q], b, acc[c], 0, 0, 0);
        }
    }
    __syncthreads();
#pragma unroll
    for (int c = 0; c < 8; c++) {
#pragma unroll
        for (int r = 0; r < 4; r++) {
            int rl = w * 16 + quad * 4 + r;
            lds[rl * 136 + c * 16 + lr] = f2bf(acc[c][r]);
        }
    }
    __syncthreads();
#pragma unroll
    for (int j = 0; j < 4; j++) {
        int idx = t + j * 256;                   // 1024 slots = 64 rows x 16 uint4
        int rl = idx >> 4, sl = idx & 15;
        int grow = gb * 64 + rl;
        if (grow < n) {
            uint4 v = *(const uint4*)&lds[rl * 136 + sl * 8];
            ((uint4*)(H + (size_t)grow * DIM))[sl] = v;
        }
    }
}

__global__ __launch_bounds__(256) void csr_k(const uint* __restrict__ stage,
                                             const int* __restrict__ bbase,
                                             int* __restrict__ row_ptr,
                                             float* __restrict__ dis,
                                             int* __restrict__ col) {
    __shared__ int hist[BWID];
    __shared__ int excl[BWID];
    __shared__ int ws[256];
    int b = blockIdx.x, t = threadIdx.x;
    int beg = bbase[b], end = bbase[b + 1];
    for (int i = t; i < BWID; i += 256) hist[i] = 0;
    __syncthreads();
    for (int i = beg + t; i < end; i += 256)
        atomicAdd(&hist[stage[i] & (BWID - 1)], 1);
    __syncthreads();
    int s = hist[2 * t] + hist[2 * t + 1];
    ws[t] = s;
    __syncthreads();
    for (int o = 1; o < 256; o <<= 1) {
        int v = ws[t];
        int add = (t >= o) ? ws[t - o] : 0;
        __syncthreads();
        ws[t] = v + add;
        __syncthreads();
    }
    int pre = (t == 0) ? 0 : ws[t - 1];
    excl[2 * t] = pre;
    excl[2 * t + 1] = pre + hist[2 * t];
    __syncthreads();
    int node0 = b * BWID;
    for (int i = t; i < BWID; i += 256) {
        int node = node0 + i;
        if (node < N_NODES) {
            row_ptr[node] = beg + excl[i];
            dis[node] = rsqrtf((float)(hist[i] + 1));   // +1 = self-loop
        } else if (node == N_NODES) {
            row_ptr[node] = beg + excl[i];
        }
    }
    __syncthreads();
    for (int i = t; i < BWID; i += 256) hist[i] = excl[i];
    __syncthreads();
    for (int i = beg + t; i < end; i += 256) {
        uint p = stage[i];
        int d9 = p & (BWID - 1);
        int r = atomicAdd(&hist[d9], 1);
        col[beg + r] = (int)(p >> BW_LOG);
    }
}

// ---------------- fused agg(layer i) + gemm(layer i+1) ----------------
// Round-4 rationale: the pull-gather is pinned at ~50us/pass by a random-access
// service-rate ceiling (R0-R3 all ~50us despite ILP/request/residency changes).
// So overlap the GEMM under it: each block aggregates its 64 rows (fp32,
// bias+ReLU), stages them in LDS, and runs the split-W MFMA GEMM in-block. MFMA
// waves of blocks in the GEMM phase co-schedule with gather-stalled waves.
// EDGE_DIS=true: Hin is raw (layer1), weight = dis[c] per edge (broadcast, ~free);
// false: Hin pre-folded by previous epilogue, weight = 1.
// Epilogue folds dis[row] into Hout for the NEXT layer's plain-sum gather.

template <bool EDGE_DIS>
__global__ __launch_bounds__(256) void fused_agg_gemm_k(
    const ushort* __restrict__ Hin, const int* __restrict__ row_ptr,
    const int* __restrict__ col, const float* __restrict__ dis,
    const float* __restrict__ bias, const ushort* __restrict__ Whi,
    const ushort* __restrict__ Wlo, ushort* __restrict__ Hout, int n) {
    __shared__ __align__(16) ushort wlds[128 * 136];   // 34.8 KB
    __shared__ __align__(16) ushort alds[64 * 136];    // 17.4 KB
    int t = threadIdx.x;

    // ---- phase A: aggregate 64 rows, 4 lanes/node x 32 feats ----
    int nl = t >> 2;                       // local row 0..63
    int lane = t & 3;                      // feats [lane*32, lane*32+32)
    int node = blockIdx.x * 64 + nl;
    int cnode = node < n ? node : n - 1;   // clamp (pad rows recompute n-1; harmless)
    float dn = dis[cnode];
    int beg = row_ptr[cnode], end = row_ptr[cnode + 1];

    float acc[32];
    {
        float ws = EDGE_DIS ? dn : 1.f;    // self-loop weight
        const ushort* rp = Hin + (size_t)cnode * DIM + lane * 32;
#pragma unroll
        for (int k = 0; k < 4; k++) {
            uint4 pv = *(const uint4*)(rp + k * 8);
            acc[k * 8 + 0] = ws * bflo(pv.x); acc[k * 8 + 1] = ws * bfhi(pv.x);
            acc[k * 8 + 2] = ws * bflo(pv.y); acc[k * 8 + 3] = ws * bfhi(pv.y);
            acc[k * 8 + 4] = ws * bflo(pv.z); acc[k * 8 + 5] = ws * bfhi(pv.z);
            acc[k * 8 + 6] = ws * bflo(pv.w); acc[k * 8 + 7] = ws * bfhi(pv.w);
        }
    }
    for (int e = beg; e < end; e += 4) {
        int ii[4];
        float wv[4];
#pragma unroll
        for (int j = 0; j < 4; j++) {
            int idx = e + j;
            wv[j] = (idx < end) ? 1.f : 0.f;
            ii[j] = idx < end ? idx : end - 1;
        }
        int c4[4];
#pragma unroll
        for (int j = 0; j < 4; j++) c4[j] = col[ii[j]];
        if (EDGE_DIS) {
#pragma unroll
            for (int j = 0; j < 4; j++) wv[j] *= dis[c4[j]];
        }
#pragma unroll
        for (int j = 0; j < 4; j++) {
            const ushort* rp = Hin + (size_t)c4[j] * DIM + lane * 32;
            float wj = wv[j];
#pragma unroll
            for (int k = 0; k < 4; k++) {
                uint4 pv = *(const uint4*)(rp + k * 8);
                acc[k * 8 + 0] += wj * bflo(pv.x); acc[k * 8 + 1] += wj * bfhi(pv.x);
                acc[k * 8 + 2] += wj * bflo(pv.y); acc[k * 8 + 3] += wj * bfhi(pv.y);
                acc[k * 8 + 4] += wj * bflo(pv.z); acc[k * 8 + 5] += wj * bfhi(pv.z);
                acc[k * 8 + 6] += wj * bflo(pv.w); acc[k * 8 + 7] += wj * bfhi(pv.w);
            }
        }
    }
    // bias + ReLU, pack to LDS as the GEMM A tile
#pragma unroll
    for (int k = 0; k < 4; k++) {
        float y0 = fmaxf(acc[k * 8 + 0] * dn + bias[lane * 32 + k * 8 + 0], 0.f);
        float y1 = fmaxf(acc[k * 8 + 1] * dn + bias[lane * 32 + k * 8 + 1], 0.f);
        float y2 = fmaxf(acc[k * 8 + 2] * dn + bias[lane * 32 + k * 8 + 2], 0.f);
        float y3 = fmaxf(acc[k * 8 + 3] * dn + bias[lane * 32 + k * 8 + 3], 0.f);
        float y4 = fmaxf(acc[k * 8 + 4] * dn + bias[lane * 32 + k * 8 + 4], 0.f);
        float y5 = fmaxf(acc[k * 8 + 5] * dn + bias[lane * 32 + k * 8 + 5], 0.f);
        float y6 = fmaxf(acc[k * 8 + 6] * dn + bias[lane * 32 + k * 8 + 6], 0.f);
        float y7 = fmaxf(acc[k * 8 + 7] * dn + bias[lane * 32 + k * 8 + 7], 0.f);
        uint4 o;
        o.x = (uint)f2bf(y0) | ((uint)f2bf(y1) << 16);
        o.y = (uint)f2bf(y2) | ((uint)f2bf(y3) << 16);
        o.z = (uint)f2bf(y4) | ((uint)f2bf(y5) << 16);
        o.w = (uint)f2bf(y6) | ((uint)f2bf(y7) << 16);
        *(uint4*)&alds[nl * 136 + lane * 32 + k * 8] = o;
    }

    // ---- phase B: gemm (64 x 128) @ (128 x 128), split-precision W ----
    auto stageW = [&](const ushort* Wsw) {
#pragma unroll
        for (int j = 0; j < 8; j++) {
            int idx8 = t + j * 256;
            int nn = idx8 >> 4;
            int k0 = (idx8 & 15) * 8;
            uint4 v = ((const uint4*)Wsw)[idx8];
            *(uint4*)&wlds[nn * 136 + k0] = v;
        }
    };
    stageW(Whi);
    __syncthreads();

    int w = t >> 6, l = t & 63;
    int quad = l >> 4, lr = l & 15;
    int arl = w * 16 + lr;                 // local A row
    bf16x8 a[4];
#pragma unroll
    for (int q = 0; q < 4; q++)
        a[q] = *(const bf16x8*)&alds[arl * 136 + q * 32 + quad * 8];

    f32x4 gacc[8];
#pragma unroll
    for (int c = 0; c < 8; c++) gacc[c] = (f32x4){0.f, 0.f, 0.f, 0.f};

#pragma unroll
    for (int q = 0; q < 4; q++) {
#pragma unroll
        for (int c = 0; c < 8; c++) {
            bf16x8 b = *(const bf16x8*)&wlds[(c * 16 + lr) * 136 + q * 32 + quad * 8];
            gacc[c] = __builtin_amdgcn_mfma_f32_16x16x32_bf16(a[q], b, gacc[c], 0, 0, 0);
        }
    }
    __syncthreads();
    stageW(Wlo);
    __syncthreads();
#pragma unroll
    for (int q = 0; q < 4; q++) {
#pragma unroll
        for (int c = 0; c < 8; c++) {
            bf16x8 b = *(const bf16x8*)&wlds[(c * 16 + lr) * 136 + q * 32 + quad * 8];
            gacc[c] = __builtin_amdgcn_mfma_f32_16x16x32_bf16(a[q], b, gacc[c], 0, 0, 0);
        }
    }

    // epilogue: fold dis[row] for the next layer (C/D row = w*16 + quad*4 + r)
    float dsc[4];
    int orow0 = blockIdx.x * 64 + w * 16 + quad * 4;
#pragma unroll
    for (int r = 0; r < 4; r++) {
        int rr = orow0 + r;
        if (rr > n - 1) rr = n - 1;
        dsc[r] = dis[rr];
    }
    __syncthreads();                       // all alds reads done (a-frags in regs)
#pragma unroll
    for (int c = 0; c < 8; c++) {
#pragma unroll
        for (int r = 0; r < 4; r++) {
            int rl = w * 16 + quad * 4 + r;
            alds[rl * 136 + c * 16 + lr] = f2bf(gacc[c][r] * dsc[r]);
        }
    }
    __syncthreads();
#pragma unroll
    for (int j = 0; j < 4; j++) {
        int idx = t + j * 256;             // 1024 slots = 64 rows x 16 uint4
        int rl = idx >> 4, sl = idx & 15;
        int grow = blockIdx.x * 64 + rl;
        if (grow < n) {
            uint4 v = *(const uint4*)&alds[rl * 136 + sl * 8];
            ((uint4*)(Hout + (size_t)grow * DIM))[sl] = v;
        }
    }
}

// ---------------- layer-3 agg fused with global_add_pool ----------------
// H pre-folded by fused3's epilogue -> plain-sum gather, 16 lanes/node, 8-edge
// unroll + predicated tail. LDS run-reduction over sorted batch ids, one global
// atomic per (run x feature).

__global__ __launch_bounds__(256) void agg_pool_k(const ushort* __restrict__ H,
                                                  const int* __restrict__ row_ptr,
                                                  const int* __restrict__ col,
                                                  const float* __restrict__ dis,
                                                  const float* __restrict__ bias,
                                                  const int* __restrict__ batch,
                                                  float* __restrict__ Out, int n) {
    __shared__ float sacc[DIM];
    int t = threadIdx.x;
    int node = blockIdx.x * 16 + (t >> 4);
    int lane = t & 15;
    int d0 = lane * 8;
    float a0 = 0.f, a1 = 0.f, a2 = 0.f, a3 = 0.f, a4 = 0.f, a5 = 0.f, a6 = 0.f, a7 = 0.f;
    int g = -1;
    if (node < n) {
        const ushort* Hl = H + lane * 8;
        float dn = dis[node];
        int beg = row_ptr[node], end = row_ptr[node + 1];
        uint4 pw = *(const uint4*)(Hl + (size_t)node * DIM);
        a0 = bflo(pw.x); a1 = bfhi(pw.x);
        a2 = bflo(pw.y); a3 = bfhi(pw.y);
        a4 = bflo(pw.z); a5 = bfhi(pw.z);
        a6 = bflo(pw.w); a7 = bfhi(pw.w);
        for (int e = beg; e < end; e += 8) {
            int c_[8];
            float w_[8];
            uint4 p_[8];
#pragma unroll
            for (int j = 0; j < 8; j++) {
                int idx = e + j;
                w_[j] = (idx < end) ? 1.f : 0.f;
                idx = idx < end ? idx : end - 1;
                c_[j] = col[idx];
            }
#pragma unroll
            for (int j = 0; j < 8; j++) p_[j] = *(const uint4*)(Hl + (size_t)c_[j] * DIM);
#pragma unroll
            for (int j = 0; j < 8; j++) {
                a0 += w_[j] * bflo(p_[j].x); a1 += w_[j] * bfhi(p_[j].x);
                a2 += w_[j] * bflo(p_[j].y); a3 += w_[j] * bfhi(p_[j].y);
                a4 += w_[j] * bflo(p_[j].z); a5 += w_[j] * bfhi(p_[j].z);
                a6 += w_[j] * bflo(p_[j].w); a7 += w_[j] * bfhi(p_[j].w);
            }
        }
        a0 = fmaxf(a0 * dn + bias[d0 + 0], 0.f);
        a1 = fmaxf(a1 * dn + bias[d0 + 1], 0.f);
        a2 = fmaxf(a2 * dn + bias[d0 + 2], 0.f);
        a3 = fmaxf(a3 * dn + bias[d0 + 3], 0.f);
        a4 = fmaxf(a4 * dn + bias[d0 + 4], 0.f);
        a5 = fmaxf(a5 * dn + bias[d0 + 5], 0.f);
        a6 = fmaxf(a6 * dn + bias[d0 + 6], 0.f);
        a7 = fmaxf(a7 * dn + bias[d0 + 7], 0.f);
        g = batch[node];
    }
    int first = blockIdx.x * 16;                       // always < n (grid = n/16)
    int last = first + 15 < n ? first + 15 : n - 1;
    int g0 = batch[first], g1 = batch[last];
    for (int gr = g0; gr <= g1; gr++) {
        if (t < DIM) sacc[t] = 0.f;
        __syncthreads();
        if (g == gr) {
            atomicAdd(&sacc[d0], a0);
            atomicAdd(&sacc[d0 + 1], a1);
            atomicAdd(&sacc[d0 + 2], a2);
            atomicAdd(&sacc[d0 + 3], a3);
            atomicAdd(&sacc[d0 + 4], a4);
            atomicAdd(&sacc[d0 + 5], a5);
            atomicAdd(&sacc[d0 + 6], a6);
            atomicAdd(&sacc[d0 + 7], a7);
        }
        __syncthreads();
        if (t < DIM) atomicAdd(&Out[gr * DIM + t], sacc[t]);
        __syncthreads();
    }
}

// ---------------- launch ----------------

extern "C" void kernel_launch(void* const* d_in, const int* in_sizes, int n_in,
                              void* d_out, int out_size, void* d_ws, size_t ws_size,
                              hipStream_t stream) {
    const float* x  = (const float*)d_in[0];
    const float* W1 = (const float*)d_in[1];
    const float* b1 = (const float*)d_in[2];
    const float* W2 = (const float*)d_in[3];
    const float* b2 = (const float*)d_in[4];
    const float* W3 = (const float*)d_in[5];
    const float* b3 = (const float*)d_in[6];
    const int*   ei = (const int*)d_in[7];
    const int*   bv = (const int*)d_in[8];
    float* out = (float*)d_out;

    const int N = N_NODES, E = N_EDGES;

    char* p = (char*)d_ws;
    auto alloc = [&](size_t bytes) -> void* {
        void* r = (void*)p;
        p += (bytes + 255) & ~(size_t)255;
        return r;
    };
    int*    bcnt_pad = (int*)alloc((size_t)NB * 16 * 4);
    int*    bcur_pad = (int*)alloc((size_t)NB * 16 * 4);
    int*    bbase    = (int*)alloc((size_t)(NB + 1) * 4);
    int*    row_ptr  = (int*)alloc((size_t)(N + 1) * 4);
    float*  dis      = (float*)alloc((size_t)N * 4);
    uint*   stage    = (uint*)alloc((size_t)E * 4);
    int*    col      = (int*)alloc((size_t)E * 4);
    ushort* B1       = (ushort*)alloc((size_t)N_PAD * DIM * 2);
    ushort* B2       = (ushort*)alloc((size_t)N_PAD * DIM * 2);
    ushort* Whi      = (ushort*)alloc((size_t)3 * DIM * DIM * 2);  // own buffer now
    ushort* Wlo      = (ushort*)alloc((size_t)3 * DIM * DIM * 2);  // (stage live at wconv)

    const int* src = ei;
    const int* dst = ei + E;

    hipMemsetAsync(d_out, 0, (size_t)N_GRAPHS * DIM * sizeof(float), stream);
    hipMemsetAsync(bcnt_pad, 0, (size_t)NB * 16 * 4, stream);

    // bhist + wconv (independent) in one dispatch
    bhist_wconv_k<<<NCHUNK + 192, 256, 0, stream>>>(dst, bcnt_pad, E, W1, W2, W3, Whi, Wlo);
    bscan_k<<<1, 128, 0, stream>>>(bcnt_pad, bbase, bcur_pad);
    // bscat + gemm1 (independent) in one dispatch; H1 = raw bf16(X @ W1) into B1
    bscat_gemm1_k<<<NCHUNK + N_PAD / 64, 256, 0, stream>>>(src, dst, bcur_pad, stage, E,
                                                           x, Whi, Wlo, B1, N);
    csr_k<<<NB, 256, 0, stream>>>(stage, bbase, row_ptr, dis, col);

    int gg = N_PAD / 64;   // 782
    // layer-1 agg (edge-dis weights on raw H1) + layer-2 gemm; H2 folded with dis
    fused_agg_gemm_k<true><<<gg, 256, 0, stream>>>(B1, row_ptr, col, dis, b1,
                                                   Whi + (size_t)DIM * DIM,
                                                   Wlo + (size_t)DIM * DIM, B2, N);
    // layer-2 agg (plain sum) + layer-3 gemm; H3 folded with dis
    fused_agg_gemm_k<false><<<gg, 256, 0, stream>>>(B2, row_ptr, col, dis, b2,
                                                    Whi + (size_t)2 * DIM * DIM,
                                                    Wlo + (size_t)2 * DIM * DIM, B1, N);
    // layer-3 agg + global_add_pool
    agg_pool_k<<<(N + 15) / 16, 256, 0, stream>>>(B1, row_ptr, col, dis, b3, bv, out, N);
}